// Round 1
// baseline (517.317 us; speedup 1.0000x reference)
//
#include <hip/hip_runtime.h>
#include <hip/hip_bf16.h>

#define B_ 4
#define S_ 2048
#define D_ 1024
#define H_ 16
#define DH_ 64
#define QBLK 64
#define KVBLK 64
#define EPS_ 1e-12f

typedef __attribute__((ext_vector_type(8))) short bf16x8;
typedef __attribute__((ext_vector_type(4))) float f32x4;

static __device__ inline unsigned short f2bf(float f) {
    __hip_bfloat16 h = __float2bfloat16(f);
    return *reinterpret_cast<unsigned short*>(&h);
}

// ---------------------------------------------------------------------------
// Projection: per (token, head) lane computes q,k,v rows (64 each).
// Writes q,k UNNORMALIZED bf16 [B][H][S][DH]; v bf16 TRANSPOSED [B][H][DH][S];
// invq = scale/max(||q||,eps), invk = 1/max(||k||,eps) as f32 [B][H][S].
// ---------------------------------------------------------------------------
__global__ __launch_bounds__(256) void proj_kernel(
    const float* __restrict__ x,
    const float* __restrict__ Wq, const float* __restrict__ bq,
    const float* __restrict__ Wk, const float* __restrict__ bk,
    const float* __restrict__ Wv, const float* __restrict__ bv,
    const float* __restrict__ temp,
    unsigned short* __restrict__ q_ws, unsigned short* __restrict__ k_ws,
    unsigned short* __restrict__ v_ws,
    float* __restrict__ invq, float* __restrict__ invk)
{
    const int h   = blockIdx.y;
    const int tok = blockIdx.x * 256 + threadIdx.x;   // 0..B*S-1
    const int b   = tok >> 11;                        // S_=2048
    const int s   = tok & (S_ - 1);
    const int bh  = b * H_ + h;

    // x slice for this (token, head): 64 f32 into registers
    float xr[DH_];
    {
        const float4* xp = reinterpret_cast<const float4*>(x + (size_t)tok * D_ + h * DH_);
#pragma unroll
        for (int i = 0; i < DH_ / 4; ++i) {
            float4 t = xp[i];
            xr[4*i+0] = t.x; xr[4*i+1] = t.y; xr[4*i+2] = t.z; xr[4*i+3] = t.w;
        }
    }
    const float* wq  = Wq + h * DH_ * DH_;
    const float* wk  = Wk + h * DH_ * DH_;
    const float* wv  = Wv + h * DH_ * DH_;
    const float* bqp = bq + h * DH_;
    const float* bkp = bk + h * DH_;
    const float* bvp = bv + h * DH_;

    const size_t qkrow = ((size_t)bh * S_ + s) * DH_;

    float sq = 0.f, sk = 0.f;
    for (int e0 = 0; e0 < DH_; e0 += 4) {   // 16 iterations (dynamic)
        float aq[4], ak[4], av[4];
#pragma unroll
        for (int j = 0; j < 4; ++j) { aq[j] = bqp[e0+j]; ak[j] = bkp[e0+j]; av[j] = bvp[e0+j]; }
#pragma unroll
        for (int d = 0; d < DH_; ++d) {
            float xv = xr[d];
#pragma unroll
            for (int j = 0; j < 4; ++j) {
                aq[j] = fmaf(xv, wq[(e0+j)*DH_ + d], aq[j]);
                ak[j] = fmaf(xv, wk[(e0+j)*DH_ + d], ak[j]);
                av[j] = fmaf(xv, wv[(e0+j)*DH_ + d], av[j]);
            }
        }
#pragma unroll
        for (int j = 0; j < 4; ++j) { sq += aq[j]*aq[j]; sk += ak[j]*ak[j]; }

        ushort4 qp, kp;
        qp.x = f2bf(aq[0]); qp.y = f2bf(aq[1]); qp.z = f2bf(aq[2]); qp.w = f2bf(aq[3]);
        kp.x = f2bf(ak[0]); kp.y = f2bf(ak[1]); kp.z = f2bf(ak[2]); kp.w = f2bf(ak[3]);
        *reinterpret_cast<ushort4*>(q_ws + qkrow + e0) = qp;
        *reinterpret_cast<ushort4*>(k_ws + qkrow + e0) = kp;
        // v transposed: [bh][e][s] — lanes (consecutive s) coalesce each store
#pragma unroll
        for (int j = 0; j < 4; ++j)
            v_ws[((size_t)bh * DH_ + (e0 + j)) * S_ + s] = f2bf(av[j]);
    }

    float scale = fmaxf(temp[h], 0.01f);
    invq[(size_t)bh * S_ + s] = scale / fmaxf(sqrtf(sq), EPS_);
    invk[(size_t)bh * S_ + s] = 1.0f  / fmaxf(sqrtf(sk), EPS_);
}

// ---------------------------------------------------------------------------
// Attention: block = 4 waves, QBLK=64 q-rows (16/wave), loop KV tiles of 64.
// Logits bounded in [-1,1] -> no online max needed: acc  O += exp(s)*V, l += exp(s).
// ---------------------------------------------------------------------------
__global__ __launch_bounds__(256) void attn_kernel(
    const unsigned short* __restrict__ q_ws, const unsigned short* __restrict__ k_ws,
    const unsigned short* __restrict__ v_ws,
    const float* __restrict__ invq, const float* __restrict__ invk,
    float* __restrict__ out)
{
    __shared__ unsigned short K_lds[KVBLK][DH_ + 8];
    __shared__ unsigned short V_lds[DH_][KVBLK + 8];
    __shared__ unsigned short P_lds[4][16][KVBLK + 8];

    // XCD-chunked swizzle: 32 consecutive q-tiles of one (b,h) stay on one XCD
    const int nwg = gridDim.x;                  // 2048, divisible by 8
    const int w   = (blockIdx.x & 7) * (nwg >> 3) + (blockIdx.x >> 3);
    const int qt  = w & 31;                     // 32 q-tiles per (b,h)
    const int bh  = w >> 5;

    const int wave = threadIdx.x >> 6;
    const int lane = threadIdx.x & 63;
    const int c = lane & 15, g = lane >> 4;
    const int qrow0 = qt * QBLK + wave * 16;

    const unsigned short* qbase = q_ws + (size_t)bh * S_ * DH_;
    const unsigned short* kbase = k_ws + (size_t)bh * S_ * DH_;
    const unsigned short* vbase = v_ws + (size_t)bh * DH_ * S_;

    // Q fragments (A-layout: row = lane&15, k = g*8+i), held for whole kernel
    bf16x8 qa[2];
    qa[0] = *reinterpret_cast<const bf16x8*>(qbase + (size_t)(qrow0 + c) * DH_ + 0  + g * 8);
    qa[1] = *reinterpret_cast<const bf16x8*>(qbase + (size_t)(qrow0 + c) * DH_ + 32 + g * 8);

    float invq4[4];
#pragma unroll
    for (int j = 0; j < 4; ++j)
        invq4[j] = invq[(size_t)bh * S_ + qrow0 + 4 * g + j];

    f32x4 o[4];
    float l[4] = {0.f, 0.f, 0.f, 0.f};
#pragma unroll
    for (int m = 0; m < 4; ++m) o[m] = (f32x4){0.f, 0.f, 0.f, 0.f};

    const int r0 = threadIdx.x >> 3;   // 0..31
    const int ch = threadIdx.x & 7;    // 0..7 (16B chunks)

    for (int kt = 0; kt < S_ / KVBLK; ++kt) {
        // ---- stage K [kv][dh] and V^T [dh][kv] tiles (coalesced 16B/lane) ----
#pragma unroll
        for (int p = 0; p < 2; ++p) {
            int row = r0 + 32 * p;
            *reinterpret_cast<bf16x8*>(&K_lds[row][ch * 8]) =
                *reinterpret_cast<const bf16x8*>(kbase + (size_t)(kt * KVBLK + row) * DH_ + ch * 8);
            *reinterpret_cast<bf16x8*>(&V_lds[row][ch * 8]) =
                *reinterpret_cast<const bf16x8*>(vbase + (size_t)row * S_ + kt * KVBLK + ch * 8);
        }
        __syncthreads();

        // ---- QK^T (16x16x32 MFMA) + exp, stash P (bf16) in per-wave LDS ----
#pragma unroll
        for (int n = 0; n < 4; ++n) {
            f32x4 sacc = (f32x4){0.f, 0.f, 0.f, 0.f};
#pragma unroll
            for (int ks = 0; ks < 2; ++ks) {
                bf16x8 kb = *reinterpret_cast<const bf16x8*>(&K_lds[n * 16 + c][ks * 32 + g * 8]);
                sacc = __builtin_amdgcn_mfma_f32_16x16x32_bf16(qa[ks], kb, sacc, 0, 0, 0);
            }
            float ikc = invk[(size_t)bh * S_ + kt * KVBLK + n * 16 + c];
#pragma unroll
            for (int j = 0; j < 4; ++j) {
                float p = __expf(sacc[j] * invq4[j] * ikc);
                l[j] += p;
                P_lds[wave][4 * g + j][n * 16 + c] = f2bf(p);
            }
        }

        // ---- PV: P (A-layout) x V (B-layout) ----
#pragma unroll
        for (int ks = 0; ks < 2; ++ks) {
            bf16x8 pa = *reinterpret_cast<const bf16x8*>(&P_lds[wave][c][ks * 32 + g * 8]);
#pragma unroll
            for (int m = 0; m < 4; ++m) {
                bf16x8 vb = *reinterpret_cast<const bf16x8*>(&V_lds[m * 16 + c][ks * 32 + g * 8]);
                o[m] = __builtin_amdgcn_mfma_f32_16x16x32_bf16(pa, vb, o[m], 0, 0, 0);
            }
        }
        __syncthreads();
    }

    // reduce softmax denominator across the 16-lane column group
#pragma unroll
    for (int j = 0; j < 4; ++j) {
        float v = l[j];
        v += __shfl_xor(v, 1); v += __shfl_xor(v, 2);
        v += __shfl_xor(v, 4); v += __shfl_xor(v, 8);
        l[j] = 1.0f / v;
    }

    const int b = bh >> 4, h = bh & 15;
#pragma unroll
    for (int m = 0; m < 4; ++m)
#pragma unroll
        for (int j = 0; j < 4; ++j) {
            int srow = qrow0 + 4 * g + j;
            out[(size_t)(b * S_ + srow) * D_ + h * DH_ + m * 16 + c] = o[m][j] * l[j];
        }
}

// ---------------------------------------------------------------------------
extern "C" void kernel_launch(void* const* d_in, const int* in_sizes, int n_in,
                              void* d_out, int out_size, void* d_ws, size_t ws_size,
                              hipStream_t stream) {
    const float* x    = (const float*)d_in[0];
    const float* Wq   = (const float*)d_in[1];
    const float* bq   = (const float*)d_in[2];
    const float* Wk   = (const float*)d_in[3];
    const float* bk   = (const float*)d_in[4];
    const float* Wv   = (const float*)d_in[5];
    const float* bv   = (const float*)d_in[6];
    const float* temp = (const float*)d_in[7];
    float* out = (float*)d_out;

    const size_t QKV_ELEMS = (size_t)B_ * H_ * S_ * DH_;   // 8388608
    unsigned short* q_ws = (unsigned short*)d_ws;
    unsigned short* k_ws = q_ws + QKV_ELEMS;
    unsigned short* v_ws = k_ws + QKV_ELEMS;
    float* invq = (float*)(v_ws + QKV_ELEMS);
    float* invk = invq + (size_t)B_ * H_ * S_;
    // total ws use: 3*8388608*2 + 2*524288*4 = ~54.5 MB

    dim3 gp(B_ * S_ / 256, H_);
    proj_kernel<<<gp, 256, 0, stream>>>(x, Wq, bq, Wk, bk, Wv, bv, temp,
                                        q_ws, k_ws, v_ws, invq, invk);

    dim3 ga(B_ * H_ * (S_ / QBLK));   // 2048 blocks
    attn_kernel<<<ga, 256, 0, stream>>>(q_ws, k_ws, v_ws, invq, invk, out);
}

// Round 2
// 227.362 us; speedup vs baseline: 2.2753x; 2.2753x over previous
//
#include <hip/hip_runtime.h>
#include <hip/hip_bf16.h>

#define B_ 4
#define S_ 2048
#define D_ 1024
#define H_ 16
#define DH_ 64
#define QBLK 64
#define KVBLK 64
#define EPS_ 1e-12f

typedef __attribute__((ext_vector_type(8))) short bf16x8;
typedef __attribute__((ext_vector_type(4))) float f32x4;

static __device__ inline unsigned short f2bf(float f) {
    __hip_bfloat16 h = __float2bfloat16(f);
    return *reinterpret_cast<unsigned short*>(&h);
}

// ---------------------------------------------------------------------------
// Cast Wq|Wk|Wv (each H*DH*DH f32) to bf16 into one contiguous buffer.
// ---------------------------------------------------------------------------
__global__ __launch_bounds__(256) void wcast_kernel(
    const float* __restrict__ Wq, const float* __restrict__ Wk,
    const float* __restrict__ Wv, unsigned short* __restrict__ wbf)
{
    const int idx = blockIdx.x * 256 + threadIdx.x;   // 0..49151
    const int i = idx * 4;                            // elem index, 3*65536 total
    const int mat = i >> 16;
    const int off = i & 65535;
    const float* src = (mat == 0) ? Wq : (mat == 1) ? Wk : Wv;
    float4 v = *reinterpret_cast<const float4*>(src + off);
    ushort4 o;
    o.x = f2bf(v.x); o.y = f2bf(v.y); o.z = f2bf(v.z); o.w = f2bf(v.w);
    *reinterpret_cast<ushort4*>(wbf + i) = o;
}

// ---------------------------------------------------------------------------
// MFMA projection: block = (64-token tile, head), 4 waves x 16 tokens.
// Writes q,k bf16 [B][H][S][DH] (unnormalized), v bf16 transposed [B][H][DH][S],
// invq = scale/max(||q||,eps), invk = 1/max(||k||,eps) f32 [B][H][S].
// ---------------------------------------------------------------------------
__global__ __launch_bounds__(256) void proj_kernel(
    const float* __restrict__ x, const unsigned short* __restrict__ wbf,
    const float* __restrict__ bq, const float* __restrict__ bk,
    const float* __restrict__ bv, const float* __restrict__ temp,
    unsigned short* __restrict__ q_ws, unsigned short* __restrict__ k_ws,
    unsigned short* __restrict__ v_ws,
    float* __restrict__ invq, float* __restrict__ invk)
{
    __shared__ unsigned short x_lds[64][72];    // [tok][d], +8 pad
    __shared__ unsigned short vt_lds[64][72];   // [e][tok], +8 pad

    const int h    = blockIdx.y;
    const int tok0 = blockIdx.x * 64;           // 0..8191, within one b
    const int b    = tok0 >> 11;
    const int s0   = tok0 & (S_ - 1);
    const int bh   = b * H_ + h;
    const int t    = threadIdx.x;
    const int wave = t >> 6, lane = t & 63, c = lane & 15, g = lane >> 4;

    // ---- stage x tile as bf16 into LDS (coalesced float4 loads) ----
    {
        const int row = t >> 2, seg = t & 3;
        const float* xp = x + (size_t)(tok0 + row) * D_ + h * DH_ + seg * 16;
#pragma unroll
        for (int i = 0; i < 4; ++i) {
            float4 v = *reinterpret_cast<const float4*>(xp + i * 4);
            ushort4 o;
            o.x = f2bf(v.x); o.y = f2bf(v.y); o.z = f2bf(v.z); o.w = f2bf(v.w);
            *reinterpret_cast<ushort4*>(&x_lds[row][seg * 16 + i * 4]) = o;
        }
    }
    __syncthreads();

    // A fragments: this wave's 16 tokens, full K=64 (shared by q,k,v)
    bf16x8 a0 = *reinterpret_cast<const bf16x8*>(&x_lds[wave * 16 + c][g * 8]);
    bf16x8 a1 = *reinterpret_cast<const bf16x8*>(&x_lds[wave * 16 + c][32 + g * 8]);

    const size_t qkrow0 = (size_t)bh * S_ + s0 + wave * 16;  // wave's first token
    const float scale = fmaxf(temp[h], 0.01f);

#pragma unroll
    for (int mat = 0; mat < 3; ++mat) {
        const unsigned short* wb = wbf + mat * (H_ * DH_ * DH_) + h * (DH_ * DH_);
        const float* bias = ((mat == 0) ? bq : (mat == 1) ? bk : bv) + h * DH_;

        f32x4 acc[4];
#pragma unroll
        for (int m = 0; m < 4; ++m) acc[m] = (f32x4){0.f, 0.f, 0.f, 0.f};
#pragma unroll
        for (int m = 0; m < 4; ++m) {
            bf16x8 b0 = *reinterpret_cast<const bf16x8*>(wb + (m * 16 + c) * DH_ + g * 8);
            bf16x8 b1 = *reinterpret_cast<const bf16x8*>(wb + (m * 16 + c) * DH_ + 32 + g * 8);
            acc[m] = __builtin_amdgcn_mfma_f32_16x16x32_bf16(a0, b0, acc[m], 0, 0, 0);
            acc[m] = __builtin_amdgcn_mfma_f32_16x16x32_bf16(a1, b1, acc[m], 0, 0, 0);
        }
#pragma unroll
        for (int m = 0; m < 4; ++m) {
            float bm = bias[m * 16 + c];
#pragma unroll
            for (int j = 0; j < 4; ++j) acc[m][j] += bm;
        }

        if (mat < 2) {
            // row norms: sum over 4 col-tiles (regs) then 16-lane reduce
            float p[4];
#pragma unroll
            for (int j = 0; j < 4; ++j) {
                p[j] = acc[0][j] * acc[0][j] + acc[1][j] * acc[1][j] +
                       acc[2][j] * acc[2][j] + acc[3][j] * acc[3][j];
                p[j] += __shfl_xor(p[j], 1); p[j] += __shfl_xor(p[j], 2);
                p[j] += __shfl_xor(p[j], 4); p[j] += __shfl_xor(p[j], 8);
            }
            if (c == 0) {
                float sc = (mat == 0) ? scale : 1.0f;
                float4 iv;
                iv.x = sc / fmaxf(sqrtf(p[0]), EPS_);
                iv.y = sc / fmaxf(sqrtf(p[1]), EPS_);
                iv.z = sc / fmaxf(sqrtf(p[2]), EPS_);
                iv.w = sc / fmaxf(sqrtf(p[3]), EPS_);
                float* invp = (mat == 0) ? invq : invk;
                *reinterpret_cast<float4*>(&invp[qkrow0 + 4 * g]) = iv;
            }
            unsigned short* dst = (mat == 0) ? q_ws : k_ws;
#pragma unroll
            for (int m = 0; m < 4; ++m)
#pragma unroll
                for (int j = 0; j < 4; ++j)
                    dst[(qkrow0 + 4 * g + j) * DH_ + m * 16 + c] = f2bf(acc[m][j]);
        } else {
            // v: stash transposed [e][tok] in LDS (ushort4 over j = consecutive toks)
#pragma unroll
            for (int m = 0; m < 4; ++m) {
                ushort4 o;
                o.x = f2bf(acc[m][0]); o.y = f2bf(acc[m][1]);
                o.z = f2bf(acc[m][2]); o.w = f2bf(acc[m][3]);
                *reinterpret_cast<ushort4*>(&vt_lds[m * 16 + c][wave * 16 + 4 * g]) = o;
            }
        }
    }
    __syncthreads();

    // coalesced v^T store: thread -> (e = t>>2, 16-token chunk = t&3)
    {
        const int e = t >> 2, ch = t & 3;
        bf16x8 v0 = *reinterpret_cast<const bf16x8*>(&vt_lds[e][ch * 16]);
        bf16x8 v1 = *reinterpret_cast<const bf16x8*>(&vt_lds[e][ch * 16 + 8]);
        unsigned short* vp = v_ws + ((size_t)bh * DH_ + e) * S_ + s0 + ch * 16;
        *reinterpret_cast<bf16x8*>(vp) = v0;
        *reinterpret_cast<bf16x8*>(vp + 8) = v1;
    }
}

// ---------------------------------------------------------------------------
// Attention: block = 4 waves, QBLK=64 q-rows (16/wave), loop KV tiles of 64.
// Logits bounded in [-1,1] -> no online max: O += exp(s)*V, l += exp(s).
// ---------------------------------------------------------------------------
__global__ __launch_bounds__(256) void attn_kernel(
    const unsigned short* __restrict__ q_ws, const unsigned short* __restrict__ k_ws,
    const unsigned short* __restrict__ v_ws,
    const float* __restrict__ invq, const float* __restrict__ invk,
    float* __restrict__ out)
{
    __shared__ unsigned short K_lds[KVBLK][DH_ + 8];
    __shared__ unsigned short V_lds[DH_][KVBLK + 8];
    __shared__ unsigned short P_lds[4][16][KVBLK + 8];

    const int nwg = gridDim.x;                  // 2048, divisible by 8
    const int w   = (blockIdx.x & 7) * (nwg >> 3) + (blockIdx.x >> 3);
    const int qt  = w & 31;
    const int bh  = w >> 5;

    const int wave = threadIdx.x >> 6;
    const int lane = threadIdx.x & 63;
    const int c = lane & 15, g = lane >> 4;
    const int qrow0 = qt * QBLK + wave * 16;

    const unsigned short* qbase = q_ws + (size_t)bh * S_ * DH_;
    const unsigned short* kbase = k_ws + (size_t)bh * S_ * DH_;
    const unsigned short* vbase = v_ws + (size_t)bh * DH_ * S_;

    bf16x8 qa[2];
    qa[0] = *reinterpret_cast<const bf16x8*>(qbase + (size_t)(qrow0 + c) * DH_ + 0  + g * 8);
    qa[1] = *reinterpret_cast<const bf16x8*>(qbase + (size_t)(qrow0 + c) * DH_ + 32 + g * 8);

    float invq4[4];
#pragma unroll
    for (int j = 0; j < 4; ++j)
        invq4[j] = invq[(size_t)bh * S_ + qrow0 + 4 * g + j];

    f32x4 o[4];
    float l[4] = {0.f, 0.f, 0.f, 0.f};
#pragma unroll
    for (int m = 0; m < 4; ++m) o[m] = (f32x4){0.f, 0.f, 0.f, 0.f};

    const int r0 = threadIdx.x >> 3;
    const int ch = threadIdx.x & 7;

    for (int kt = 0; kt < S_ / KVBLK; ++kt) {
#pragma unroll
        for (int p = 0; p < 2; ++p) {
            int row = r0 + 32 * p;
            *reinterpret_cast<bf16x8*>(&K_lds[row][ch * 8]) =
                *reinterpret_cast<const bf16x8*>(kbase + (size_t)(kt * KVBLK + row) * DH_ + ch * 8);
            *reinterpret_cast<bf16x8*>(&V_lds[row][ch * 8]) =
                *reinterpret_cast<const bf16x8*>(vbase + (size_t)row * S_ + kt * KVBLK + ch * 8);
        }
        __syncthreads();

#pragma unroll
        for (int n = 0; n < 4; ++n) {
            f32x4 sacc = (f32x4){0.f, 0.f, 0.f, 0.f};
#pragma unroll
            for (int ks = 0; ks < 2; ++ks) {
                bf16x8 kb = *reinterpret_cast<const bf16x8*>(&K_lds[n * 16 + c][ks * 32 + g * 8]);
                sacc = __builtin_amdgcn_mfma_f32_16x16x32_bf16(qa[ks], kb, sacc, 0, 0, 0);
            }
            float ikc = invk[(size_t)bh * S_ + kt * KVBLK + n * 16 + c];
#pragma unroll
            for (int j = 0; j < 4; ++j) {
                float p = __expf(sacc[j] * invq4[j] * ikc);
                l[j] += p;
                P_lds[wave][4 * g + j][n * 16 + c] = f2bf(p);
            }
        }

#pragma unroll
        for (int ks = 0; ks < 2; ++ks) {
            bf16x8 pa = *reinterpret_cast<const bf16x8*>(&P_lds[wave][c][ks * 32 + g * 8]);
#pragma unroll
            for (int m = 0; m < 4; ++m) {
                bf16x8 vb = *reinterpret_cast<const bf16x8*>(&V_lds[m * 16 + c][ks * 32 + g * 8]);
                o[m] = __builtin_amdgcn_mfma_f32_16x16x32_bf16(pa, vb, o[m], 0, 0, 0);
            }
        }
        __syncthreads();
    }

#pragma unroll
    for (int j = 0; j < 4; ++j) {
        float v = l[j];
        v += __shfl_xor(v, 1); v += __shfl_xor(v, 2);
        v += __shfl_xor(v, 4); v += __shfl_xor(v, 8);
        l[j] = 1.0f / v;
    }

    const int b = bh >> 4, h = bh & 15;
#pragma unroll
    for (int m = 0; m < 4; ++m)
#pragma unroll
        for (int j = 0; j < 4; ++j) {
            int srow = qrow0 + 4 * g + j;
            out[(size_t)(b * S_ + srow) * D_ + h * DH_ + m * 16 + c] = o[m][j] * l[j];
        }
}

// ---------------------------------------------------------------------------
extern "C" void kernel_launch(void* const* d_in, const int* in_sizes, int n_in,
                              void* d_out, int out_size, void* d_ws, size_t ws_size,
                              hipStream_t stream) {
    const float* x    = (const float*)d_in[0];
    const float* Wq   = (const float*)d_in[1];
    const float* bq   = (const float*)d_in[2];
    const float* Wk   = (const float*)d_in[3];
    const float* bk   = (const float*)d_in[4];
    const float* Wv   = (const float*)d_in[5];
    const float* bv   = (const float*)d_in[6];
    const float* temp = (const float*)d_in[7];
    float* out = (float*)d_out;

    const size_t QKV_ELEMS = (size_t)B_ * H_ * S_ * DH_;   // 8388608
    unsigned short* q_ws = (unsigned short*)d_ws;
    unsigned short* k_ws = q_ws + QKV_ELEMS;
    unsigned short* v_ws = k_ws + QKV_ELEMS;
    float* invq = (float*)(v_ws + QKV_ELEMS);
    float* invk = invq + (size_t)B_ * H_ * S_;
    // ws use: 3*16.8MB + 2*2.1MB ~= 54.5 MB

    // bf16 weights parked in d_out (attn fully overwrites d_out afterwards)
    unsigned short* wbf = (unsigned short*)d_out;   // 3*65536 bf16 = 384 KB

    wcast_kernel<<<192, 256, 0, stream>>>(Wq, Wk, Wv, wbf);

    dim3 gp(B_ * S_ / 64, H_);      // 128 x 16
    proj_kernel<<<gp, 256, 0, stream>>>(x, wbf, bq, bk, bv, temp,
                                        q_ws, k_ws, v_ws, invq, invk);

    dim3 ga(B_ * H_ * (S_ / QBLK)); // 2048 blocks
    attn_kernel<<<ga, 256, 0, stream>>>(q_ws, k_ws, v_ws, invq, invk, out);
}

// Round 3
// 149.321 us; speedup vs baseline: 3.4645x; 1.5226x over previous
//
#include <hip/hip_runtime.h>
#include <hip/hip_bf16.h>

#define B_ 4
#define S_ 2048
#define D_ 1024
#define H_ 16
#define DH_ 64
#define QBLK 128
#define KVBLK 64
#define NT (S_ / KVBLK)
#define EPS_ 1e-12f
#define LOG2E_ 1.44269504f

typedef __attribute__((ext_vector_type(8))) short bf16x8;
typedef __attribute__((ext_vector_type(4))) float f32x4;

static __device__ __forceinline__ unsigned short f2bf(float f) {
    __hip_bfloat16 h = __float2bfloat16(f);
    return *reinterpret_cast<unsigned short*>(&h);
}

static __device__ __forceinline__ float fast_exp2(float x) {
#if __has_builtin(__builtin_amdgcn_exp2f)
    return __builtin_amdgcn_exp2f(x);
#else
    return exp2f(x);
#endif
}

// swizzled chunk index: tiles are [row][64] ushort = 8 chunks of 16B per row.
// chunk' = chunk ^ (row&7) spreads a column-slice read across all bank quads.
static __device__ __forceinline__ int swz(int row, int chunk) {
    return (row << 6) + ((chunk ^ (row & 7)) << 3);
}

// ---------------------------------------------------------------------------
// Cast Wq|Wk|Wv (each H*DH*DH f32) to bf16 into one contiguous buffer.
// ---------------------------------------------------------------------------
__global__ __launch_bounds__(256) void wcast_kernel(
    const float* __restrict__ Wq, const float* __restrict__ Wk,
    const float* __restrict__ Wv, unsigned short* __restrict__ wbf)
{
    const int idx = blockIdx.x * 256 + threadIdx.x;
    const int i = idx * 4;
    const int mat = i >> 16;
    const int off = i & 65535;
    const float* src = (mat == 0) ? Wq : (mat == 1) ? Wk : Wv;
    float4 v = *reinterpret_cast<const float4*>(src + off);
    ushort4 o;
    o.x = f2bf(v.x); o.y = f2bf(v.y); o.z = f2bf(v.z); o.w = f2bf(v.w);
    *reinterpret_cast<ushort4*>(wbf + i) = o;
}

// ---------------------------------------------------------------------------
// MFMA projection. Stores NORMALIZED q,k:
//   q_hat = q * max(temp,0.01) * log2(e) / max(||q||,eps)   (bf16, [B][H][S][DH])
//   k_hat = k / max(||k||,eps)                              (bf16, [B][H][S][DH])
//   v transposed bf16 [B][H][DH][S]
// so attention is just exp2(QK^T) with no per-element scales.
// ---------------------------------------------------------------------------
__global__ __launch_bounds__(256) void proj_kernel(
    const float* __restrict__ x, const unsigned short* __restrict__ wbf,
    const float* __restrict__ bq, const float* __restrict__ bk,
    const float* __restrict__ bv, const float* __restrict__ temp,
    unsigned short* __restrict__ q_ws, unsigned short* __restrict__ k_ws,
    unsigned short* __restrict__ v_ws)
{
    __shared__ unsigned short x_lds[64][72];
    __shared__ unsigned short vt_lds[64][72];

    const int h    = blockIdx.y;
    const int tok0 = blockIdx.x * 64;
    const int b    = tok0 >> 11;
    const int s0   = tok0 & (S_ - 1);
    const int bh   = b * H_ + h;
    const int t    = threadIdx.x;
    const int wave = t >> 6, lane = t & 63, c = lane & 15, g = lane >> 4;

    {
        const int row = t >> 2, seg = t & 3;
        const float* xp = x + (size_t)(tok0 + row) * D_ + h * DH_ + seg * 16;
#pragma unroll
        for (int i = 0; i < 4; ++i) {
            float4 v = *reinterpret_cast<const float4*>(xp + i * 4);
            ushort4 o;
            o.x = f2bf(v.x); o.y = f2bf(v.y); o.z = f2bf(v.z); o.w = f2bf(v.w);
            *reinterpret_cast<ushort4*>(&x_lds[row][seg * 16 + i * 4]) = o;
        }
    }
    __syncthreads();

    bf16x8 a0 = *reinterpret_cast<const bf16x8*>(&x_lds[wave * 16 + c][g * 8]);
    bf16x8 a1 = *reinterpret_cast<const bf16x8*>(&x_lds[wave * 16 + c][32 + g * 8]);

    const size_t qkrow0 = (size_t)bh * S_ + s0 + wave * 16;
    const float scaleq = fmaxf(temp[h], 0.01f) * LOG2E_;

#pragma unroll
    for (int mat = 0; mat < 3; ++mat) {
        const unsigned short* wb = wbf + mat * (H_ * DH_ * DH_) + h * (DH_ * DH_);
        const float* bias = ((mat == 0) ? bq : (mat == 1) ? bk : bv) + h * DH_;

        f32x4 acc[4];
#pragma unroll
        for (int m = 0; m < 4; ++m) acc[m] = (f32x4){0.f, 0.f, 0.f, 0.f};
#pragma unroll
        for (int m = 0; m < 4; ++m) {
            bf16x8 b0 = *reinterpret_cast<const bf16x8*>(wb + (m * 16 + c) * DH_ + g * 8);
            bf16x8 b1 = *reinterpret_cast<const bf16x8*>(wb + (m * 16 + c) * DH_ + 32 + g * 8);
            acc[m] = __builtin_amdgcn_mfma_f32_16x16x32_bf16(a0, b0, acc[m], 0, 0, 0);
            acc[m] = __builtin_amdgcn_mfma_f32_16x16x32_bf16(a1, b1, acc[m], 0, 0, 0);
        }
#pragma unroll
        for (int m = 0; m < 4; ++m) {
            float bm = bias[m * 16 + c];
#pragma unroll
            for (int j = 0; j < 4; ++j) acc[m][j] += bm;
        }

        if (mat < 2) {
            float rinv[4];
            const float sc = (mat == 0) ? scaleq : 1.0f;
#pragma unroll
            for (int j = 0; j < 4; ++j) {
                float p = acc[0][j] * acc[0][j] + acc[1][j] * acc[1][j] +
                          acc[2][j] * acc[2][j] + acc[3][j] * acc[3][j];
                p += __shfl_xor(p, 1); p += __shfl_xor(p, 2);
                p += __shfl_xor(p, 4); p += __shfl_xor(p, 8);
                rinv[j] = sc / fmaxf(sqrtf(p), EPS_);
            }
            unsigned short* dst = (mat == 0) ? q_ws : k_ws;
#pragma unroll
            for (int m = 0; m < 4; ++m)
#pragma unroll
                for (int j = 0; j < 4; ++j)
                    dst[(qkrow0 + 4 * g + j) * DH_ + m * 16 + c] = f2bf(acc[m][j] * rinv[j]);
        } else {
#pragma unroll
            for (int m = 0; m < 4; ++m) {
                ushort4 o;
                o.x = f2bf(acc[m][0]); o.y = f2bf(acc[m][1]);
                o.z = f2bf(acc[m][2]); o.w = f2bf(acc[m][3]);
                *reinterpret_cast<ushort4*>(&vt_lds[m * 16 + c][wave * 16 + 4 * g]) = o;
            }
        }
    }
    __syncthreads();

    {
        const int e = t >> 2, ch = t & 3;
        bf16x8 v0 = *reinterpret_cast<const bf16x8*>(&vt_lds[e][ch * 16]);
        bf16x8 v1 = *reinterpret_cast<const bf16x8*>(&vt_lds[e][ch * 16 + 8]);
        unsigned short* vp = v_ws + ((size_t)bh * DH_ + e) * S_ + s0 + ch * 16;
        *reinterpret_cast<bf16x8*>(vp) = v0;
        *reinterpret_cast<bf16x8*>(vp + 8) = v1;
    }
}

// ---------------------------------------------------------------------------
// Attention: 4 waves x 32 q-rows (QBLK=128), KV tiles of 64, swizzled LDS.
// Logits pre-scaled by log2e -> p = exp2(sacc). No online max (|logit|<=1.45).
// ---------------------------------------------------------------------------
__global__ __launch_bounds__(256) void attn_kernel(
    const unsigned short* __restrict__ q_ws, const unsigned short* __restrict__ k_ws,
    const unsigned short* __restrict__ v_ws, float* __restrict__ out)
{
    __shared__ unsigned short K_lds[64 * 64];
    __shared__ unsigned short V_lds[64 * 64];
    __shared__ unsigned short P_lds[4 * 32 * 64];

    const int nwg = gridDim.x;                         // 1024, %8 == 0
    const int w   = (blockIdx.x & 7) * (nwg >> 3) + (blockIdx.x >> 3);
    const int qt  = w & 15;                            // 16 q-tiles per (b,h)
    const int bh  = w >> 4;

    const int t = threadIdx.x;
    const int wave = t >> 6, lane = t & 63, c = lane & 15, g = lane >> 4;
    const int qrow0 = qt * QBLK + wave * 32;

    const unsigned short* qbase = q_ws + (size_t)bh * S_ * DH_;
    const unsigned short* kbase = k_ws + (size_t)bh * S_ * DH_;
    const unsigned short* vbase = v_ws + (size_t)bh * DH_ * S_;

    // Q fragments [qi][ks] — wave's 32 q-rows, held in regs all kernel
    bf16x8 qa[2][2];
#pragma unroll
    for (int qi = 0; qi < 2; ++qi)
#pragma unroll
        for (int ks = 0; ks < 2; ++ks)
            qa[qi][ks] = *reinterpret_cast<const bf16x8*>(
                qbase + (size_t)(qrow0 + qi * 16 + c) * DH_ + ks * 32 + g * 8);

    unsigned short* pw = P_lds + wave * (32 * 64);

    // staging: thread -> (row, two 16B chunks)
    const int srow = t >> 2, sch = (t & 3) * 2;
    bf16x8 kr0, kr1, vr0, vr1;
    auto load_tile = [&](int kt) {
        const unsigned short* kp = kbase + (size_t)(kt * KVBLK + srow) * DH_ + sch * 8;
        kr0 = *reinterpret_cast<const bf16x8*>(kp);
        kr1 = *reinterpret_cast<const bf16x8*>(kp + 8);
        const unsigned short* vp = vbase + (size_t)srow * S_ + kt * KVBLK + sch * 8;
        vr0 = *reinterpret_cast<const bf16x8*>(vp);
        vr1 = *reinterpret_cast<const bf16x8*>(vp + 8);
    };
    load_tile(0);

    f32x4 o[2][4];
    float l[2][4];
#pragma unroll
    for (int qi = 0; qi < 2; ++qi)
#pragma unroll
        for (int m = 0; m < 4; ++m) {
            o[qi][m] = (f32x4){0.f, 0.f, 0.f, 0.f};
            l[qi][m] = 0.f;
        }

    for (int kt = 0; kt < NT; ++kt) {
        // write staged tile (swizzled)
        *reinterpret_cast<bf16x8*>(&K_lds[swz(srow, sch)])     = kr0;
        *reinterpret_cast<bf16x8*>(&K_lds[swz(srow, sch + 1)]) = kr1;
        *reinterpret_cast<bf16x8*>(&V_lds[swz(srow, sch)])     = vr0;
        *reinterpret_cast<bf16x8*>(&V_lds[swz(srow, sch + 1)]) = vr1;
        __syncthreads();
        if (kt + 1 < NT) load_tile(kt + 1);   // prefetch hides under compute

        // ---- QK^T + exp2 -> P (per-wave, swizzled) ----
#pragma unroll
        for (int n = 0; n < 4; ++n) {
            f32x4 s0 = (f32x4){0.f, 0.f, 0.f, 0.f};
            f32x4 s1 = (f32x4){0.f, 0.f, 0.f, 0.f};
#pragma unroll
            for (int ks = 0; ks < 2; ++ks) {
                bf16x8 kb = *reinterpret_cast<const bf16x8*>(&K_lds[swz(n * 16 + c, ks * 4 + g)]);
                s0 = __builtin_amdgcn_mfma_f32_16x16x32_bf16(qa[0][ks], kb, s0, 0, 0, 0);
                s1 = __builtin_amdgcn_mfma_f32_16x16x32_bf16(qa[1][ks], kb, s1, 0, 0, 0);
            }
            const int pchunk = n * 2 + (c >> 3);
            const int pelem  = c & 7;
#pragma unroll
            for (int j = 0; j < 4; ++j) {
                float p0 = fast_exp2(s0[j]); l[0][j] += p0;
                float p1 = fast_exp2(s1[j]); l[1][j] += p1;
                const int r = 4 * g + j;
                pw[swz(r, pchunk) + pelem]      = f2bf(p0);
                pw[swz(r + 16, pchunk) + pelem] = f2bf(p1);
            }
        }

        // ---- PV ----
#pragma unroll
        for (int ks = 0; ks < 2; ++ks) {
            bf16x8 pa0 = *reinterpret_cast<const bf16x8*>(&pw[swz(c, ks * 4 + g)]);
            bf16x8 pa1 = *reinterpret_cast<const bf16x8*>(&pw[swz(16 + c, ks * 4 + g)]);
#pragma unroll
            for (int m = 0; m < 4; ++m) {
                bf16x8 vb = *reinterpret_cast<const bf16x8*>(&V_lds[swz(m * 16 + c, ks * 4 + g)]);
                o[0][m] = __builtin_amdgcn_mfma_f32_16x16x32_bf16(pa0, vb, o[0][m], 0, 0, 0);
                o[1][m] = __builtin_amdgcn_mfma_f32_16x16x32_bf16(pa1, vb, o[1][m], 0, 0, 0);
            }
        }
        __syncthreads();
    }

    // softmax denominators: reduce across the 16 kv-column lanes (same g)
#pragma unroll
    for (int qi = 0; qi < 2; ++qi)
#pragma unroll
        for (int j = 0; j < 4; ++j) {
            float v = l[qi][j];
            v += __shfl_xor(v, 1); v += __shfl_xor(v, 2);
            v += __shfl_xor(v, 4); v += __shfl_xor(v, 8);
            l[qi][j] = 1.0f / v;
        }

    const int bb = bh >> 4, hh = bh & 15;
#pragma unroll
    for (int qi = 0; qi < 2; ++qi)
#pragma unroll
        for (int m = 0; m < 4; ++m)
#pragma unroll
            for (int j = 0; j < 4; ++j) {
                const int srow_ = qrow0 + qi * 16 + 4 * g + j;
                out[(size_t)(bb * S_ + srow_) * D_ + hh * DH_ + m * 16 + c] =
                    o[qi][m][j] * l[qi][j];
            }
}

// ---------------------------------------------------------------------------
extern "C" void kernel_launch(void* const* d_in, const int* in_sizes, int n_in,
                              void* d_out, int out_size, void* d_ws, size_t ws_size,
                              hipStream_t stream) {
    const float* x    = (const float*)d_in[0];
    const float* Wq   = (const float*)d_in[1];
    const float* bq   = (const float*)d_in[2];
    const float* Wk   = (const float*)d_in[3];
    const float* bk   = (const float*)d_in[4];
    const float* Wv   = (const float*)d_in[5];
    const float* bv   = (const float*)d_in[6];
    const float* temp = (const float*)d_in[7];
    float* out = (float*)d_out;

    const size_t QKV_ELEMS = (size_t)B_ * H_ * S_ * DH_;   // 8388608
    unsigned short* q_ws = (unsigned short*)d_ws;
    unsigned short* k_ws = q_ws + QKV_ELEMS;
    unsigned short* v_ws = k_ws + QKV_ELEMS;
    // ws use: 3 * 16.8 MB ~= 50 MB

    unsigned short* wbf = (unsigned short*)d_out;   // parked; attn overwrites d_out

    wcast_kernel<<<192, 256, 0, stream>>>(Wq, Wk, Wv, wbf);

    dim3 gp(B_ * S_ / 64, H_);
    proj_kernel<<<gp, 256, 0, stream>>>(x, wbf, bq, bk, bv, temp, q_ws, k_ws, v_ws);

    dim3 ga(B_ * H_ * (S_ / QBLK));   // 1024 blocks = 4/CU exactly
    attn_kernel<<<ga, 256, 0, stream>>>(q_ws, k_ws, v_ws, out);
}

// Round 4
// 115.179 us; speedup vs baseline: 4.4914x; 1.2964x over previous
//
#include <hip/hip_runtime.h>
#include <hip/hip_bf16.h>

#define B_ 4
#define S_ 2048
#define D_ 1024
#define H_ 16
#define DH_ 64
#define QBLK 128
#define KVBLK 64
#define NT (S_ / KVBLK)
#define EPS_ 1e-12f
#define LOG2E_ 1.44269504f

typedef __attribute__((ext_vector_type(8))) short bf16x8;
typedef __attribute__((ext_vector_type(4))) float f32x4;

static __device__ __forceinline__ unsigned short f2bf(float f) {
    __hip_bfloat16 h = __float2bfloat16(f);
    return *reinterpret_cast<unsigned short*>(&h);
}

static __device__ __forceinline__ float fast_exp2(float x) {
#if __has_builtin(__builtin_amdgcn_exp2f)
    return __builtin_amdgcn_exp2f(x);
#else
    return exp2f(x);
#endif
}

// pack two f32 -> one u32 of 2 bf16 (lo in low half), RNE
static __device__ __forceinline__ unsigned int cvt_pk_bf16(float lo, float hi) {
    unsigned int r;
    asm("v_cvt_pk_bf16_f32 %0, %1, %2" : "=v"(r) : "v"(lo), "v"(hi));
    return r;
}

// swizzled chunk index: tiles are [row][64] ushort = 8 chunks of 16B per row.
static __device__ __forceinline__ int swz(int row, int chunk) {
    return (row << 6) + ((chunk ^ (row & 7)) << 3);
}

// k-row permutation (within 32-row blocks): label kk -> storage row, so that
// swapped-QK^T C-registers come out in PV A-fragment packing order.
// perm(8g+4nn+j) = 16nn+4g+j
static __device__ __forceinline__ int kperm(int kk) {
    return ((kk & 4) << 2) | ((kk >> 1) & 12) | (kk & 3);
}

// ---------------------------------------------------------------------------
__global__ __launch_bounds__(256) void wcast_kernel(
    const float* __restrict__ Wq, const float* __restrict__ Wk,
    const float* __restrict__ Wv, unsigned short* __restrict__ wbf)
{
    const int idx = blockIdx.x * 256 + threadIdx.x;
    const int i = idx * 4;
    const int mat = i >> 16;
    const int off = i & 65535;
    const float* src = (mat == 0) ? Wq : (mat == 1) ? Wk : Wv;
    float4 v = *reinterpret_cast<const float4*>(src + off);
    ushort4 o;
    o.x = f2bf(v.x); o.y = f2bf(v.y); o.z = f2bf(v.z); o.w = f2bf(v.w);
    *reinterpret_cast<ushort4*>(wbf + i) = o;
}

// ---------------------------------------------------------------------------
// MFMA projection. Stores NORMALIZED q,k (q pre-scaled by temp*log2e), v^T.
// k rows are stored PERMUTED within 32-token blocks (kperm) for the attn
// in-register-P path. v and q are unpermuted.
// ---------------------------------------------------------------------------
__global__ __launch_bounds__(256) void proj_kernel(
    const float* __restrict__ x, const unsigned short* __restrict__ wbf,
    const float* __restrict__ bq, const float* __restrict__ bk,
    const float* __restrict__ bv, const float* __restrict__ temp,
    unsigned short* __restrict__ q_ws, unsigned short* __restrict__ k_ws,
    unsigned short* __restrict__ v_ws)
{
    __shared__ unsigned short x_lds[64][72];
    __shared__ unsigned short vt_lds[64][72];

    const int h    = blockIdx.y;
    const int tok0 = blockIdx.x * 64;
    const int b    = tok0 >> 11;
    const int s0   = tok0 & (S_ - 1);
    const int bh   = b * H_ + h;
    const int t    = threadIdx.x;
    const int wave = t >> 6, lane = t & 63, c = lane & 15, g = lane >> 4;

    {
        const int row = t >> 2, seg = t & 3;
        const float* xp = x + (size_t)(tok0 + row) * D_ + h * DH_ + seg * 16;
#pragma unroll
        for (int i = 0; i < 4; ++i) {
            float4 v = *reinterpret_cast<const float4*>(xp + i * 4);
            ushort4 o;
            o.x = f2bf(v.x); o.y = f2bf(v.y); o.z = f2bf(v.z); o.w = f2bf(v.w);
            *reinterpret_cast<ushort4*>(&x_lds[row][seg * 16 + i * 4]) = o;
        }
    }
    __syncthreads();

    bf16x8 a0 = *reinterpret_cast<const bf16x8*>(&x_lds[wave * 16 + c][g * 8]);
    bf16x8 a1 = *reinterpret_cast<const bf16x8*>(&x_lds[wave * 16 + c][32 + g * 8]);

    const float scaleq = fmaxf(temp[h], 0.01f) * LOG2E_;

#pragma unroll
    for (int mat = 0; mat < 3; ++mat) {
        const unsigned short* wb = wbf + mat * (H_ * DH_ * DH_) + h * (DH_ * DH_);
        const float* bias = ((mat == 0) ? bq : (mat == 1) ? bk : bv) + h * DH_;

        f32x4 acc[4];
#pragma unroll
        for (int m = 0; m < 4; ++m) acc[m] = (f32x4){0.f, 0.f, 0.f, 0.f};
#pragma unroll
        for (int m = 0; m < 4; ++m) {
            bf16x8 b0 = *reinterpret_cast<const bf16x8*>(wb + (m * 16 + c) * DH_ + g * 8);
            bf16x8 b1 = *reinterpret_cast<const bf16x8*>(wb + (m * 16 + c) * DH_ + 32 + g * 8);
            acc[m] = __builtin_amdgcn_mfma_f32_16x16x32_bf16(a0, b0, acc[m], 0, 0, 0);
            acc[m] = __builtin_amdgcn_mfma_f32_16x16x32_bf16(a1, b1, acc[m], 0, 0, 0);
        }
#pragma unroll
        for (int m = 0; m < 4; ++m) {
            float bm = bias[m * 16 + c];
#pragma unroll
            for (int j = 0; j < 4; ++j) acc[m][j] += bm;
        }

        if (mat < 2) {
            float rinv[4];
            const float sc = (mat == 0) ? scaleq : 1.0f;
#pragma unroll
            for (int j = 0; j < 4; ++j) {
                float p = acc[0][j] * acc[0][j] + acc[1][j] * acc[1][j] +
                          acc[2][j] * acc[2][j] + acc[3][j] * acc[3][j];
                p += __shfl_xor(p, 1); p += __shfl_xor(p, 2);
                p += __shfl_xor(p, 4); p += __shfl_xor(p, 8);
                rinv[j] = sc / fmaxf(sqrtf(p), EPS_);
            }
            unsigned short* dst = (mat == 0) ? q_ws : k_ws;
#pragma unroll
            for (int m = 0; m < 4; ++m)
#pragma unroll
                for (int j = 0; j < 4; ++j) {
                    int sl = wave * 16 + 4 * g + j;              // token within 64-tile
                    int row = (mat == 1) ? ((sl & ~31) | kperm(sl & 31)) : sl;
                    dst[((size_t)bh * S_ + s0 + row) * DH_ + m * 16 + c] =
                        f2bf(acc[m][j] * rinv[j]);
                }
        } else {
#pragma unroll
            for (int m = 0; m < 4; ++m) {
                ushort4 o;
                o.x = f2bf(acc[m][0]); o.y = f2bf(acc[m][1]);
                o.z = f2bf(acc[m][2]); o.w = f2bf(acc[m][3]);
                *reinterpret_cast<ushort4*>(&vt_lds[m * 16 + c][wave * 16 + 4 * g]) = o;
            }
        }
    }
    __syncthreads();

    {
        const int e = t >> 2, ch = t & 3;
        bf16x8 v0 = *reinterpret_cast<const bf16x8*>(&vt_lds[e][ch * 16]);
        bf16x8 v1 = *reinterpret_cast<const bf16x8*>(&vt_lds[e][ch * 16 + 8]);
        unsigned short* vp = v_ws + ((size_t)bh * DH_ + e) * S_ + s0 + ch * 16;
        *reinterpret_cast<bf16x8*>(vp) = v0;
        *reinterpret_cast<bf16x8*>(vp + 8) = v1;
    }
}

// ---------------------------------------------------------------------------
// Attention: 4 waves x 32 q-rows, KV tiles of 64, double-buffered LDS,
// swapped QK^T -> in-register P (zero shuffles via k-row permutation),
// one barrier per tile. p = exp2(S^T), O += P*V, l += sum(P).
// ---------------------------------------------------------------------------
__global__ __launch_bounds__(256, 4) void attn_kernel(
    const unsigned short* __restrict__ q_ws, const unsigned short* __restrict__ k_ws,
    const unsigned short* __restrict__ v_ws, float* __restrict__ out)
{
    __shared__ unsigned short K_lds[2][64 * 64];
    __shared__ unsigned short V_lds[2][64 * 64];

    const int nwg = gridDim.x;                         // 1024, %8 == 0
    const int w   = (blockIdx.x & 7) * (nwg >> 3) + (blockIdx.x >> 3);
    const int qt  = w & 15;
    const int bh  = w >> 4;

    const int t = threadIdx.x;
    const int lane = t & 63, c = lane & 15, g = lane >> 4;
    const int wave = t >> 6;
    const int qrow0 = qt * QBLK + wave * 32;

    const unsigned short* qbase = q_ws + (size_t)bh * S_ * DH_;
    const unsigned short* kbase = k_ws + (size_t)bh * S_ * DH_;
    const unsigned short* vbase = v_ws + (size_t)bh * DH_ * S_;

    // Q fragments (B-operand of swapped QK^T): [qi][kd]
    bf16x8 qa[2][2];
#pragma unroll
    for (int qi = 0; qi < 2; ++qi)
#pragma unroll
        for (int kd = 0; kd < 2; ++kd)
            qa[qi][kd] = *reinterpret_cast<const bf16x8*>(
                qbase + (size_t)(qrow0 + qi * 16 + c) * DH_ + kd * 32 + g * 8);

    // staging: thread -> (row, two 16B chunks)
    const int srow = t >> 2, sch = (t & 3) * 2;
    bf16x8 kr0, kr1, vr0, vr1;
    auto load_tile = [&](int kt) {
        const unsigned short* kp = kbase + (size_t)(kt * KVBLK + srow) * DH_ + sch * 8;
        kr0 = *reinterpret_cast<const bf16x8*>(kp);
        kr1 = *reinterpret_cast<const bf16x8*>(kp + 8);
        const unsigned short* vp = vbase + (size_t)srow * S_ + kt * KVBLK + sch * 8;
        vr0 = *reinterpret_cast<const bf16x8*>(vp);
        vr1 = *reinterpret_cast<const bf16x8*>(vp + 8);
    };
    auto store_tile = [&](int buf) {
        *reinterpret_cast<bf16x8*>(&K_lds[buf][swz(srow, sch)])     = kr0;
        *reinterpret_cast<bf16x8*>(&K_lds[buf][swz(srow, sch + 1)]) = kr1;
        *reinterpret_cast<bf16x8*>(&V_lds[buf][swz(srow, sch)])     = vr0;
        *reinterpret_cast<bf16x8*>(&V_lds[buf][swz(srow, sch + 1)]) = vr1;
    };

    load_tile(0);
    store_tile(0);
    __syncthreads();

    f32x4 o[2][4];
    float l[2] = {0.f, 0.f};
#pragma unroll
    for (int qi = 0; qi < 2; ++qi)
#pragma unroll
        for (int m = 0; m < 4; ++m) o[qi][m] = (f32x4){0.f, 0.f, 0.f, 0.f};

    for (int kt = 0; kt < NT; ++kt) {
        const int cur = kt & 1;
        const bool more = (kt + 1 < NT);
        if (more) load_tile(kt + 1);

        const unsigned short* Kb = &K_lds[cur][0];
        const unsigned short* Vb = &V_lds[cur][0];

#pragma unroll
        for (int ks = 0; ks < 2; ++ks) {
            // ---- S^T = K·Q^T for this 32-k slice (2 sub-tiles nn) ----
            f32x4 s[2][2];   // [qi][nn]
#pragma unroll
            for (int nn = 0; nn < 2; ++nn) {
                const int krow = ks * 32 + nn * 16 + c;
                bf16x8 a0 = *reinterpret_cast<const bf16x8*>(&Kb[swz(krow, g)]);
                bf16x8 a1 = *reinterpret_cast<const bf16x8*>(&Kb[swz(krow, 4 + g)]);
#pragma unroll
                for (int qi = 0; qi < 2; ++qi) {
                    f32x4 acc = (f32x4){0.f, 0.f, 0.f, 0.f};
                    acc = __builtin_amdgcn_mfma_f32_16x16x32_bf16(a0, qa[qi][0], acc, 0, 0, 0);
                    acc = __builtin_amdgcn_mfma_f32_16x16x32_bf16(a1, qa[qi][1], acc, 0, 0, 0);
                    s[qi][nn] = acc;
                }
            }

            // ---- exp2 -> bf16 A-fragment (in-register, packing matches) ----
            bf16x8 pa[2];
#pragma unroll
            for (int qi = 0; qi < 2; ++qi) {
                float p0 = fast_exp2(s[qi][0][0]), p1 = fast_exp2(s[qi][0][1]);
                float p2 = fast_exp2(s[qi][0][2]), p3 = fast_exp2(s[qi][0][3]);
                float p4 = fast_exp2(s[qi][1][0]), p5 = fast_exp2(s[qi][1][1]);
                float p6 = fast_exp2(s[qi][1][2]), p7 = fast_exp2(s[qi][1][3]);
                l[qi] += ((p0 + p1) + (p2 + p3)) + ((p4 + p5) + (p6 + p7));
                union { unsigned int u[4]; bf16x8 v; } pk;
                pk.u[0] = cvt_pk_bf16(p0, p1);
                pk.u[1] = cvt_pk_bf16(p2, p3);
                pk.u[2] = cvt_pk_bf16(p4, p5);
                pk.u[3] = cvt_pk_bf16(p6, p7);
                pa[qi] = pk.v;
            }

            // ---- PV for this 32-k slice ----
#pragma unroll
            for (int m = 0; m < 4; ++m) {
                bf16x8 vb = *reinterpret_cast<const bf16x8*>(&Vb[swz(m * 16 + c, ks * 4 + g)]);
                o[0][m] = __builtin_amdgcn_mfma_f32_16x16x32_bf16(pa[0], vb, o[0][m], 0, 0, 0);
                o[1][m] = __builtin_amdgcn_mfma_f32_16x16x32_bf16(pa[1], vb, o[1][m], 0, 0, 0);
            }
        }

        if (more) store_tile(cur ^ 1);
        __syncthreads();
    }

    // denominator: lane holds partial for q=c; reduce over the 4 g-groups
    float rl[2];
#pragma unroll
    for (int qi = 0; qi < 2; ++qi) {
        float v = l[qi];
        v += __shfl_xor(v, 16);
        v += __shfl_xor(v, 32);
        rl[qi] = v;   // all lanes now hold total for q = c
    }

    const int bb = bh >> 4, hh = bh & 15;
#pragma unroll
    for (int qi = 0; qi < 2; ++qi)
#pragma unroll
        for (int j = 0; j < 4; ++j) {
            // o rows are q = 4g+j; fetch l[q=4g+j] from lane (c = 4g+j, g=0)
            float inv = 1.0f / __shfl(rl[qi], 4 * g + j);
            const int srow_ = qrow0 + qi * 16 + 4 * g + j;
            float* op = out + (size_t)(bb * S_ + srow_) * D_ + hh * DH_;
#pragma unroll
            for (int m = 0; m < 4; ++m)
                op[m * 16 + c] = o[qi][m][j] * inv;
        }
}

// ---------------------------------------------------------------------------
extern "C" void kernel_launch(void* const* d_in, const int* in_sizes, int n_in,
                              void* d_out, int out_size, void* d_ws, size_t ws_size,
                              hipStream_t stream) {
    const float* x    = (const float*)d_in[0];
    const float* Wq   = (const float*)d_in[1];
    const float* bq   = (const float*)d_in[2];
    const float* Wk   = (const float*)d_in[3];
    const float* bk   = (const float*)d_in[4];
    const float* Wv   = (const float*)d_in[5];
    const float* bv   = (const float*)d_in[6];
    const float* temp = (const float*)d_in[7];
    float* out = (float*)d_out;

    const size_t QKV_ELEMS = (size_t)B_ * H_ * S_ * DH_;   // 8388608
    unsigned short* q_ws = (unsigned short*)d_ws;
    unsigned short* k_ws = q_ws + QKV_ELEMS;
    unsigned short* v_ws = k_ws + QKV_ELEMS;

    unsigned short* wbf = (unsigned short*)d_out;   // parked; attn overwrites d_out

    wcast_kernel<<<192, 256, 0, stream>>>(Wq, Wk, Wv, wbf);

    dim3 gp(B_ * S_ / 64, H_);
    proj_kernel<<<gp, 256, 0, stream>>>(x, wbf, bq, bk, bv, temp, q_ws, k_ws, v_ws);

    dim3 ga(B_ * H_ * (S_ / QBLK));   // 1024 blocks = 4/CU
    attn_kernel<<<ga, 256, 0, stream>>>(q_ws, k_ws, v_ws, out);
}

// Round 6
// 114.287 us; speedup vs baseline: 4.5265x; 1.0078x over previous
//
#include <hip/hip_runtime.h>
#include <hip/hip_bf16.h>

#define B_ 4
#define S_ 2048
#define D_ 1024
#define H_ 16
#define DH_ 64
#define QBLK 128
#define KVBLK 64
#define NT (S_ / KVBLK)
#define EPS_ 1e-12f
#define LOG2E_ 1.44269504f

typedef __attribute__((ext_vector_type(8))) short bf16x8;
typedef __attribute__((ext_vector_type(4))) float f32x4;

static __device__ __forceinline__ unsigned short f2bf(float f) {
    __hip_bfloat16 h = __float2bfloat16(f);
    return *reinterpret_cast<unsigned short*>(&h);
}

static __device__ __forceinline__ float fast_exp2(float x) {
#if __has_builtin(__builtin_amdgcn_exp2f)
    return __builtin_amdgcn_exp2f(x);
#else
    return exp2f(x);
#endif
}

// pack two f32 -> one u32 of 2 bf16 (lo in low half), RNE
static __device__ __forceinline__ unsigned int cvt_pk_bf16(float lo, float hi) {
    unsigned int r;
    asm("v_cvt_pk_bf16_f32 %0, %1, %2" : "=v"(r) : "v"(lo), "v"(hi));
    return r;
}

// swizzled chunk index: tiles are [row][64] ushort = 8 chunks of 16B per row.
static __device__ __forceinline__ int swz(int row, int chunk) {
    return (row << 6) + ((chunk ^ (row & 7)) << 3);
}

// k-row permutation (within 32-row blocks): label kk -> storage row, so that
// swapped-QK^T C-registers come out in PV A-fragment packing order.
// perm(8g+4nn+j) = 16nn+4g+j
static __device__ __forceinline__ int kperm(int kk) {
    return ((kk & 4) << 2) | ((kk >> 1) & 12) | (kk & 3);
}

// ---------------------------------------------------------------------------
__global__ __launch_bounds__(256) void wcast_kernel(
    const float* __restrict__ Wq, const float* __restrict__ Wk,
    const float* __restrict__ Wv, unsigned short* __restrict__ wbf)
{
    const int idx = blockIdx.x * 256 + threadIdx.x;
    const int i = idx * 4;
    const int mat = i >> 16;
    const int off = i & 65535;
    const float* src = (mat == 0) ? Wq : (mat == 1) ? Wk : Wv;
    float4 v = *reinterpret_cast<const float4*>(src + off);
    ushort4 o;
    o.x = f2bf(v.x); o.y = f2bf(v.y); o.z = f2bf(v.z); o.w = f2bf(v.w);
    *reinterpret_cast<ushort4*>(wbf + i) = o;
}

// ---------------------------------------------------------------------------
// MFMA projection. Stores NORMALIZED q,k (q pre-scaled by temp*log2e), v^T.
// k rows PERMUTED within 32-token blocks (kperm). All outputs staged through
// LDS -> coalesced b128 global stores (no scalar global stores).
// ---------------------------------------------------------------------------
__global__ __launch_bounds__(256) void proj_kernel(
    const float* __restrict__ x, const unsigned short* __restrict__ wbf,
    const float* __restrict__ bq, const float* __restrict__ bk,
    const float* __restrict__ bv, const float* __restrict__ temp,
    unsigned short* __restrict__ q_ws, unsigned short* __restrict__ k_ws,
    unsigned short* __restrict__ v_ws)
{
    __shared__ unsigned short x_lds[64][72];
    __shared__ unsigned short o_lds[64][72];   // reused per mat

    const int h    = blockIdx.y;
    const int tok0 = blockIdx.x * 64;
    const int b    = tok0 >> 11;
    const int s0   = tok0 & (S_ - 1);
    const int bh   = b * H_ + h;
    const int t    = threadIdx.x;
    const int wave = t >> 6, lane = t & 63, c = lane & 15, g = lane >> 4;

    {
        const int row = t >> 2, seg = t & 3;
        const float* xp = x + (size_t)(tok0 + row) * D_ + h * DH_ + seg * 16;
#pragma unroll
        for (int i = 0; i < 4; ++i) {
            float4 v = *reinterpret_cast<const float4*>(xp + i * 4);
            ushort4 o;
            o.x = f2bf(v.x); o.y = f2bf(v.y); o.z = f2bf(v.z); o.w = f2bf(v.w);
            *reinterpret_cast<ushort4*>(&x_lds[row][seg * 16 + i * 4]) = o;
        }
    }
    __syncthreads();

    bf16x8 a0 = *reinterpret_cast<const bf16x8*>(&x_lds[wave * 16 + c][g * 8]);
    bf16x8 a1 = *reinterpret_cast<const bf16x8*>(&x_lds[wave * 16 + c][32 + g * 8]);

    const float scaleq = fmaxf(temp[h], 0.01f) * LOG2E_;
    const int srow_ = t >> 2, sch_ = t & 3;   // store mapping

#pragma unroll
    for (int mat = 0; mat < 3; ++mat) {
        const unsigned short* wb = wbf + mat * (H_ * DH_ * DH_) + h * (DH_ * DH_);
        const float* bias = ((mat == 0) ? bq : (mat == 1) ? bk : bv) + h * DH_;

        f32x4 acc[4];
#pragma unroll
        for (int m = 0; m < 4; ++m) acc[m] = (f32x4){0.f, 0.f, 0.f, 0.f};
#pragma unroll
        for (int m = 0; m < 4; ++m) {
            bf16x8 b0 = *reinterpret_cast<const bf16x8*>(wb + (m * 16 + c) * DH_ + g * 8);
            bf16x8 b1 = *reinterpret_cast<const bf16x8*>(wb + (m * 16 + c) * DH_ + 32 + g * 8);
            acc[m] = __builtin_amdgcn_mfma_f32_16x16x32_bf16(a0, b0, acc[m], 0, 0, 0);
            acc[m] = __builtin_amdgcn_mfma_f32_16x16x32_bf16(a1, b1, acc[m], 0, 0, 0);
        }
#pragma unroll
        for (int m = 0; m < 4; ++m) {
            float bm = bias[m * 16 + c];
#pragma unroll
            for (int j = 0; j < 4; ++j) acc[m][j] += bm;
        }

        if (mat < 2) {
            float rinv[4];
            const float sc = (mat == 0) ? scaleq : 1.0f;
#pragma unroll
            for (int j = 0; j < 4; ++j) {
                float p = acc[0][j] * acc[0][j] + acc[1][j] * acc[1][j] +
                          acc[2][j] * acc[2][j] + acc[3][j] * acc[3][j];
                p += __shfl_xor(p, 1); p += __shfl_xor(p, 2);
                p += __shfl_xor(p, 4); p += __shfl_xor(p, 8);
                rinv[j] = sc / fmaxf(sqrtf(p), EPS_);
            }
            // scalar LDS writes [tok(perm'd for k)][e]
#pragma unroll
            for (int m = 0; m < 4; ++m)
#pragma unroll
                for (int j = 0; j < 4; ++j) {
                    int sl = wave * 16 + 4 * g + j;
                    int row = (mat == 1) ? ((sl & ~31) | kperm(sl & 31)) : sl;
                    o_lds[row][m * 16 + c] = f2bf(acc[m][j] * rinv[j]);
                }
        } else {
            // v transposed [e][tok]
#pragma unroll
            for (int m = 0; m < 4; ++m) {
                ushort4 o;
                o.x = f2bf(acc[m][0]); o.y = f2bf(acc[m][1]);
                o.z = f2bf(acc[m][2]); o.w = f2bf(acc[m][3]);
                *reinterpret_cast<ushort4*>(&o_lds[m * 16 + c][wave * 16 + 4 * g]) = o;
            }
        }
        __syncthreads();

        // coalesced b128 stores: thread -> (row = t>>2, two 16B chunks)
        {
            bf16x8 v0 = *reinterpret_cast<const bf16x8*>(&o_lds[srow_][sch_ * 16]);
            bf16x8 v1 = *reinterpret_cast<const bf16x8*>(&o_lds[srow_][sch_ * 16 + 8]);
            unsigned short* dp;
            if (mat < 2) {
                unsigned short* dst = (mat == 0) ? q_ws : k_ws;
                dp = dst + ((size_t)bh * S_ + s0 + srow_) * DH_ + sch_ * 16;
            } else {
                dp = v_ws + ((size_t)bh * DH_ + srow_) * S_ + s0 + sch_ * 16;
            }
            *reinterpret_cast<bf16x8*>(dp) = v0;
            *reinterpret_cast<bf16x8*>(dp + 8) = v1;
        }
        if (mat < 2) __syncthreads();   // before next mat overwrites o_lds
    }
}

// ---------------------------------------------------------------------------
// Attention: 4 waves x 32 q-rows, KV tiles of 64, double-buffered LDS,
// swapped QK^T -> in-register P (zero shuffles via k-row permutation),
// one barrier per tile. Scalar f32 l-sum + shuffle epilogue (round-3 known
// good); setprio around the compute cluster.
// ---------------------------------------------------------------------------
__global__ __launch_bounds__(256, 4) void attn_kernel(
    const unsigned short* __restrict__ q_ws, const unsigned short* __restrict__ k_ws,
    const unsigned short* __restrict__ v_ws, float* __restrict__ out)
{
    __shared__ unsigned short K_lds[2][64 * 64];
    __shared__ unsigned short V_lds[2][64 * 64];

    const int nwg = gridDim.x;                         // 1024, %8 == 0
    const int w   = (blockIdx.x & 7) * (nwg >> 3) + (blockIdx.x >> 3);
    const int qt  = w & 15;
    const int bh  = w >> 4;

    const int t = threadIdx.x;
    const int lane = t & 63, c = lane & 15, g = lane >> 4;
    const int wave = t >> 6;
    const int qrow0 = qt * QBLK + wave * 32;

    const unsigned short* qbase = q_ws + (size_t)bh * S_ * DH_;
    const unsigned short* kbase = k_ws + (size_t)bh * S_ * DH_;
    const unsigned short* vbase = v_ws + (size_t)bh * DH_ * S_;

    // Q fragments (B-operand of swapped QK^T): [qi][kd]
    bf16x8 qa[2][2];
#pragma unroll
    for (int qi = 0; qi < 2; ++qi)
#pragma unroll
        for (int kd = 0; kd < 2; ++kd)
            qa[qi][kd] = *reinterpret_cast<const bf16x8*>(
                qbase + (size_t)(qrow0 + qi * 16 + c) * DH_ + kd * 32 + g * 8);

    // staging: thread -> (row, two 16B chunks)
    const int srow = t >> 2, sch = (t & 3) * 2;
    bf16x8 kr0, kr1, vr0, vr1;
    auto load_tile = [&](int kt) {
        const unsigned short* kp = kbase + (size_t)(kt * KVBLK + srow) * DH_ + sch * 8;
        kr0 = *reinterpret_cast<const bf16x8*>(kp);
        kr1 = *reinterpret_cast<const bf16x8*>(kp + 8);
        const unsigned short* vp = vbase + (size_t)srow * S_ + kt * KVBLK + sch * 8;
        vr0 = *reinterpret_cast<const bf16x8*>(vp);
        vr1 = *reinterpret_cast<const bf16x8*>(vp + 8);
    };
    auto store_tile = [&](int buf) {
        *reinterpret_cast<bf16x8*>(&K_lds[buf][swz(srow, sch)])     = kr0;
        *reinterpret_cast<bf16x8*>(&K_lds[buf][swz(srow, sch + 1)]) = kr1;
        *reinterpret_cast<bf16x8*>(&V_lds[buf][swz(srow, sch)])     = vr0;
        *reinterpret_cast<bf16x8*>(&V_lds[buf][swz(srow, sch + 1)]) = vr1;
    };

    load_tile(0);
    store_tile(0);
    __syncthreads();

    f32x4 o[2][4];
    float l[2] = {0.f, 0.f};
#pragma unroll
    for (int qi = 0; qi < 2; ++qi)
#pragma unroll
        for (int m = 0; m < 4; ++m) o[qi][m] = (f32x4){0.f, 0.f, 0.f, 0.f};

    for (int kt = 0; kt < NT; ++kt) {
        const int cur = kt & 1;
        const bool more = (kt + 1 < NT);
        if (more) load_tile(kt + 1);

        const unsigned short* Kb = &K_lds[cur][0];
        const unsigned short* Vb = &V_lds[cur][0];

        __builtin_amdgcn_s_setprio(1);
#pragma unroll
        for (int ks = 0; ks < 2; ++ks) {
            // ---- S^T = K·Q^T for this 32-k slice (2 sub-tiles nn) ----
            f32x4 s[2][2];   // [qi][nn]
#pragma unroll
            for (int nn = 0; nn < 2; ++nn) {
                const int krow = ks * 32 + nn * 16 + c;
                bf16x8 a0 = *reinterpret_cast<const bf16x8*>(&Kb[swz(krow, g)]);
                bf16x8 a1 = *reinterpret_cast<const bf16x8*>(&Kb[swz(krow, 4 + g)]);
#pragma unroll
                for (int qi = 0; qi < 2; ++qi) {
                    f32x4 acc = (f32x4){0.f, 0.f, 0.f, 0.f};
                    acc = __builtin_amdgcn_mfma_f32_16x16x32_bf16(a0, qa[qi][0], acc, 0, 0, 0);
                    acc = __builtin_amdgcn_mfma_f32_16x16x32_bf16(a1, qa[qi][1], acc, 0, 0, 0);
                    s[qi][nn] = acc;
                }
            }

            // ---- exp2 -> bf16 A-fragment (in-register, packing matches) ----
            bf16x8 pa[2];
#pragma unroll
            for (int qi = 0; qi < 2; ++qi) {
                float p0 = fast_exp2(s[qi][0][0]), p1 = fast_exp2(s[qi][0][1]);
                float p2 = fast_exp2(s[qi][0][2]), p3 = fast_exp2(s[qi][0][3]);
                float p4 = fast_exp2(s[qi][1][0]), p5 = fast_exp2(s[qi][1][1]);
                float p6 = fast_exp2(s[qi][1][2]), p7 = fast_exp2(s[qi][1][3]);
                l[qi] += ((p0 + p1) + (p2 + p3)) + ((p4 + p5) + (p6 + p7));
                union { unsigned int u[4]; bf16x8 v; } pk;
                pk.u[0] = cvt_pk_bf16(p0, p1);
                pk.u[1] = cvt_pk_bf16(p2, p3);
                pk.u[2] = cvt_pk_bf16(p4, p5);
                pk.u[3] = cvt_pk_bf16(p6, p7);
                pa[qi] = pk.v;
            }

            // ---- PV for this 32-k slice ----
#pragma unroll
            for (int m = 0; m < 4; ++m) {
                bf16x8 vb = *reinterpret_cast<const bf16x8*>(&Vb[swz(m * 16 + c, ks * 4 + g)]);
                o[0][m] = __builtin_amdgcn_mfma_f32_16x16x32_bf16(pa[0], vb, o[0][m], 0, 0, 0);
                o[1][m] = __builtin_amdgcn_mfma_f32_16x16x32_bf16(pa[1], vb, o[1][m], 0, 0, 0);
            }
        }
        __builtin_amdgcn_s_setprio(0);

        if (more) store_tile(cur ^ 1);
        __syncthreads();
    }

    // denominator: lane holds partial for q=c; reduce over the 4 g-groups
    float rl[2];
#pragma unroll
    for (int qi = 0; qi < 2; ++qi) {
        float v = l[qi];
        v += __shfl_xor(v, 16);
        v += __shfl_xor(v, 32);
        rl[qi] = v;   // all lanes now hold total for q = c
    }

    const int bb = bh >> 4, hh = bh & 15;
#pragma unroll
    for (int qi = 0; qi < 2; ++qi)
#pragma unroll
        for (int j = 0; j < 4; ++j) {
            // o rows are q = 4g+j; fetch l[q=4g+j] from lane (c = 4g+j, g=0)
            float inv = 1.0f / __shfl(rl[qi], 4 * g + j);
            const int srw = qrow0 + qi * 16 + 4 * g + j;
            float* op = out + (size_t)(bb * S_ + srw) * D_ + hh * DH_;
#pragma unroll
            for (int m = 0; m < 4; ++m)
                op[m * 16 + c] = o[qi][m][j] * inv;
        }
}

// ---------------------------------------------------------------------------
extern "C" void kernel_launch(void* const* d_in, const int* in_sizes, int n_in,
                              void* d_out, int out_size, void* d_ws, size_t ws_size,
                              hipStream_t stream) {
    const float* x    = (const float*)d_in[0];
    const float* Wq   = (const float*)d_in[1];
    const float* bq   = (const float*)d_in[2];
    const float* Wk   = (const float*)d_in[3];
    const float* bk   = (const float*)d_in[4];
    const float* Wv   = (const float*)d_in[5];
    const float* bv   = (const float*)d_in[6];
    const float* temp = (const float*)d_in[7];
    float* out = (float*)d_out;

    const size_t QKV_ELEMS = (size_t)B_ * H_ * S_ * DH_;   // 8388608
    unsigned short* q_ws = (unsigned short*)d_ws;
    unsigned short* k_ws = q_ws + QKV_ELEMS;
    unsigned short* v_ws = k_ws + QKV_ELEMS;

    unsigned short* wbf = (unsigned short*)d_out;   // parked; attn overwrites d_out

    wcast_kernel<<<192, 256, 0, stream>>>(Wq, Wk, Wv, wbf);

    dim3 gp(B_ * S_ / 64, H_);
    proj_kernel<<<gp, 256, 0, stream>>>(x, wbf, bq, bk, bv, temp, q_ws, k_ws, v_ws);

    dim3 ga(B_ * H_ * (S_ / QBLK));   // 1024 blocks = 4/CU
    attn_kernel<<<ga, 256, 0, stream>>>(q_ws, k_ws, v_ws, out);
}